// Round 4
// baseline (1901.961 us; speedup 1.0000x reference)
//
#include <hip/hip_runtime.h>

// Problem constants: T=1024, B=64, D=256, H=256, 4H=1024, D+H=512.

typedef _Float16 half2_t __attribute__((ext_vector_type(2)));
typedef _Float16 half4_t __attribute__((ext_vector_type(4)));
typedef _Float16 half8_t __attribute__((ext_vector_type(8)));
typedef float floatx4 __attribute__((ext_vector_type(4)));

__device__ __forceinline__ float fdot2(unsigned h, unsigned w, float acc) {
#if __has_builtin(__builtin_amdgcn_fdot2)
  return __builtin_amdgcn_fdot2(__builtin_bit_cast(half2_t, h),
                                __builtin_bit_cast(half2_t, w), acc, false);
#else
  half2_t a = __builtin_bit_cast(half2_t, h);
  half2_t b = __builtin_bit_cast(half2_t, w);
  return acc + (float)a[0] * (float)b[0] + (float)a[1] * (float)b[1];
#endif
}

__device__ __forceinline__ floatx4 mfma16x16x32(half8_t a, half8_t b, floatx4 c) {
#if __has_builtin(__builtin_amdgcn_mfma_f32_16x16x32_f16)
  return __builtin_amdgcn_mfma_f32_16x16x32_f16(a, b, c, 0, 0, 0);
#else
  half4_t alo = __builtin_shufflevector(a, a, 0, 1, 2, 3);
  half4_t ahi = __builtin_shufflevector(a, a, 4, 5, 6, 7);
  half4_t blo = __builtin_shufflevector(b, b, 0, 1, 2, 3);
  half4_t bhi = __builtin_shufflevector(b, b, 4, 5, 6, 7);
  c = __builtin_amdgcn_mfma_f32_16x16x16f16(alo, blo, c, 0, 0, 0);
  c = __builtin_amdgcn_mfma_f32_16x16x16f16(ahi, bhi, c, 0, 0, 0);
  return c;
#endif
}

__device__ __forceinline__ float sigm(float x) { return 1.f / (1.f + __expf(-x)); }
__device__ __forceinline__ float tanh_(float x) {
  float ax = fabsf(x);
  float e = __expf(-2.f * ax);
  float t = (1.f - e) / (1.f + e);
  return x < 0.f ? -t : t;
}

// ---------------------------------------------------------------------------
// K0: W [512][1024] f32 (row-major) -> WT [1024][512] fp16 (col-major of W).
// ---------------------------------------------------------------------------
__global__ __launch_bounds__(256) void k_transpose_w(const float* __restrict__ W,
                                                     _Float16* __restrict__ WT) {
  __shared__ float tile[64][65];
  const int bx = blockIdx.x & 15;
  const int by = blockIdx.x >> 4;
  const int c0 = bx * 64, r0 = by * 64;
  const int tid = threadIdx.x;
#pragma unroll
  for (int i = 0; i < 16; ++i) {
    int idx = tid + i * 256;
    int r = idx >> 6, c = idx & 63;
    tile[r][c] = W[(size_t)(r0 + r) * 1024 + c0 + c];
  }
  __syncthreads();
#pragma unroll
  for (int i = 0; i < 16; ++i) {
    int idx = tid + i * 256;
    int c = idx >> 6, r = idx & 63;
    WT[(size_t)(c0 + c) * 512 + r0 + r] = (_Float16)tile[r][c];
  }
}

// ---------------------------------------------------------------------------
// K1: Gx = X @ W[:256,:] + b, fp16 MFMA, f32 accum, fp16 out. BM=BN=128 BK=32.
// ---------------------------------------------------------------------------
__global__ __launch_bounds__(256) void k_gx_gemm(const float* __restrict__ X,
                                                 const _Float16* __restrict__ WT,
                                                 const float* __restrict__ bias,
                                                 _Float16* __restrict__ Gx) {
  const int nb = blockIdx.x & 7;
  const int mb = blockIdx.x >> 3;
  const int m0 = mb * 128, n0 = nb * 128;
  __shared__ __align__(16) _Float16 As[128 * 40];
  __shared__ __align__(16) _Float16 Bs[128 * 40];
  const int tid = threadIdx.x;
  const int wave = tid >> 6, lane = tid & 63;
  const int wm = (wave >> 1) * 64, wn = (wave & 1) * 64;
  const int lm = lane & 15, lg = lane >> 4;
  const int srow = tid >> 1, skh = (tid & 1) * 16;
  floatx4 acc[4][4] = {};
  for (int kt = 0; kt < 256; kt += 32) {
    __syncthreads();
    {
      const float* src = X + (size_t)(m0 + srow) * 256 + kt + skh;
      float4 f0 = ((const float4*)src)[0];
      float4 f1 = ((const float4*)src)[1];
      float4 f2 = ((const float4*)src)[2];
      float4 f3 = ((const float4*)src)[3];
      half8_t h0 = {(_Float16)f0.x, (_Float16)f0.y, (_Float16)f0.z, (_Float16)f0.w,
                    (_Float16)f1.x, (_Float16)f1.y, (_Float16)f1.z, (_Float16)f1.w};
      half8_t h1 = {(_Float16)f2.x, (_Float16)f2.y, (_Float16)f2.z, (_Float16)f2.w,
                    (_Float16)f3.x, (_Float16)f3.y, (_Float16)f3.z, (_Float16)f3.w};
      *(half8_t*)&As[srow * 40 + skh] = h0;
      *(half8_t*)&As[srow * 40 + skh + 8] = h1;
      const _Float16* bsrc = WT + (size_t)(n0 + srow) * 512 + kt + skh;
      half8_t b0 = ((const half8_t*)bsrc)[0];
      half8_t b1 = ((const half8_t*)bsrc)[1];
      *(half8_t*)&Bs[srow * 40 + skh] = b0;
      *(half8_t*)&Bs[srow * 40 + skh + 8] = b1;
    }
    __syncthreads();
    half8_t af[4], bf[4];
#pragma unroll
    for (int mf = 0; mf < 4; ++mf)
      af[mf] = *(const half8_t*)&As[(wm + mf * 16 + lm) * 40 + lg * 8];
#pragma unroll
    for (int nf = 0; nf < 4; ++nf)
      bf[nf] = *(const half8_t*)&Bs[(wn + nf * 16 + lm) * 40 + lg * 8];
#pragma unroll
    for (int mf = 0; mf < 4; ++mf)
#pragma unroll
      for (int nf = 0; nf < 4; ++nf)
        acc[mf][nf] = mfma16x16x32(af[mf], bf[nf], acc[mf][nf]);
  }
#pragma unroll
  for (int mf = 0; mf < 4; ++mf) {
#pragma unroll
    for (int nf = 0; nf < 4; ++nf) {
      const int gm = m0 + wm + mf * 16 + lg * 4;
      const int gn = n0 + wn + nf * 16 + lm;
      const float bv = bias[gn];
#pragma unroll
      for (int i = 0; i < 4; ++i)
        Gx[(size_t)(gm + i) * 1024 + gn] = (_Float16)(acc[mf][nf][i] + bv);
    }
  }
}

// ---------------------------------------------------------------------------
// K2: persistent per-batch LSTM recurrence. 64 blocks (1/CU), 512 threads.
// Thread owns gate columns {tid, tid+512}. Wh fully CU-resident:
//   rows 0..183   -> 23 uint4 x 2 cols = 184 VGPRs. R2 (launch_bounds(512,2))
//                    and R3 (waves_per_eu(2,2)) both left the allocator capped
//                    at 128 VGPRs -> weights rematerialized from L2 each step
//                    (the 1.8us/step). amdgpu_num_vgpr(256) sets the budget
//                    DIRECTLY; waves_per_eu(1) stops the occupancy heuristic
//                    from shrinking it. 256 VGPRs still = 2 waves/SIMD (m69).
//   rows 184..255 -> LDS, 1024 cols x 72 rows fp16 = 144KB.
//                    Column stride 144B -> bank (9*col+4i)%32, odd stride =>
//                    2 lanes/bank = free (m136, verified: conflicts==0 in R3).
// hx in LDS as fp16x2, uniform-address broadcast reads.
// Gx/noise prefetched one step ahead.
// ---------------------------------------------------------------------------
__global__ __attribute__((amdgpu_flat_work_group_size(512, 512),
                          amdgpu_waves_per_eu(1),
                          amdgpu_num_vgpr(256))) void
k_lstm(const _Float16* __restrict__ Gx, const _Float16* __restrict__ WT,
       const float* __restrict__ noise, const float* __restrict__ beta_p,
       float* __restrict__ out) {
  extern __shared__ char smem[];
  uint4* wl = (uint4*)smem;                     // [1024 cols][9 chunks] 144KB
  float* gates = (float*)(smem + 147456);       // 1024 f32
  unsigned* hx2 = (unsigned*)(smem + 151552);   // 128 dwords = 256 fp16 h

  const int b = blockIdx.x;
  const int tid = threadIdx.x;
  const float beta = beta_p[0];
  const int c0 = tid, c1 = tid + 512;

  // Stage weights. WT row offset +256 = h-part of the fused matrix.
  const uint4* p0 = (const uint4*)(WT + (size_t)c0 * 512 + 256);
  const uint4* p1 = (const uint4*)(WT + (size_t)c1 * 512 + 256);
  uint4 w0[23], w1[23];
#pragma unroll
  for (int i = 0; i < 23; ++i) w0[i] = p0[i];
#pragma unroll
  for (int i = 0; i < 23; ++i) w1[i] = p1[i];
  uint4* wlp0 = wl + c0 * 9;
  uint4* wlp1 = wl + c1 * 9;
#pragma unroll
  for (int i = 0; i < 9; ++i) wlp0[i] = p0[23 + i];
#pragma unroll
  for (int i = 0; i < 9; ++i) wlp1[i] = p1[23 + i];
  if (tid < 128) hx2[tid] = 0u;
  float cx = 0.f, hlast = 0.f;
  __syncthreads();

  const _Float16* gp0 = Gx + (size_t)b * 1024 + c0;
  const _Float16* gp1 = Gx + (size_t)b * 1024 + c1;
  const float* nzp = noise + (size_t)b * 256 + (tid & 255);
  float* outp = out + (size_t)b * 256 + tid;  // only used when tid<256

  // Prefetch step 0.
  float g0 = (float)gp0[0];
  float g1 = (float)gp1[0];
  float nz = nzp[0];

  for (int t = 0; t < 1024; ++t) {
    // Prefetch step t+1 (hides under the fdot2 phase).
    float g0n = 0.f, g1n = 0.f, nzn = 0.f;
    if (t < 1023) {
      g0n = (float)gp0[65536];
      g1n = (float)gp1[65536];
      nzn = nzp[16384];
    }

    float a0e = 0.f, a0o = 0.f, a1e = 0.f, a1o = 0.f;
    // Register-resident rows 0..183: chunk i = rows 8i..8i+7.
#pragma unroll
    for (int i = 0; i < 23; ++i) {
      uint4 h4 = *(const uint4*)&hx2[i * 4];  // wave-uniform -> LDS broadcast
      a0e = fdot2(h4.x, w0[i].x, a0e);
      a0o = fdot2(h4.y, w0[i].y, a0o);
      a0e = fdot2(h4.z, w0[i].z, a0e);
      a0o = fdot2(h4.w, w0[i].w, a0o);
      a1e = fdot2(h4.x, w1[i].x, a1e);
      a1o = fdot2(h4.y, w1[i].y, a1o);
      a1e = fdot2(h4.z, w1[i].z, a1e);
      a1o = fdot2(h4.w, w1[i].w, a1o);
    }
    // LDS-resident rows 184..255: chunks 23..31.
#pragma unroll
    for (int i = 0; i < 9; ++i) {
      uint4 h4 = *(const uint4*)&hx2[92 + i * 4];
      uint4 wa = wlp0[i];
      uint4 wb = wlp1[i];
      a0e = fdot2(h4.x, wa.x, a0e);
      a0o = fdot2(h4.y, wa.y, a0o);
      a0e = fdot2(h4.z, wa.z, a0e);
      a0o = fdot2(h4.w, wa.w, a0o);
      a1e = fdot2(h4.x, wb.x, a1e);
      a1o = fdot2(h4.y, wb.y, a1o);
      a1e = fdot2(h4.z, wb.z, a1e);
      a1o = fdot2(h4.w, wb.w, a1o);
    }
    gates[c0] = a0e + a0o + g0;
    gates[c1] = a1e + a1o + g1;
    __syncthreads();  // gates ready; all hx2 reads for step t done

    if (tid < 256) {
      float f = sigm(gates[tid]);
      float ii = sigm(gates[tid + 256]);
      float gg = tanh_(gates[tid + 512]);
      float oo = sigm(gates[tid + 768]);
      cx = f * cx + ii * gg;
      float h = oo * tanh_(cx) + beta * nz;
      hlast = h;
      outp[0] = h;
      ((_Float16*)hx2)[tid] = (_Float16)h;  // publish hx for step t+1
    }
    g0 = g0n; g1 = g1n; nz = nzn;
    gp0 += 65536; gp1 += 65536; nzp += 16384; outp += 16384;
    __syncthreads();  // hx2 ready
  }

  if (tid < 256) {
    out[(size_t)16777216 + (size_t)b * 256 + tid] = hlast;       // final hx
    out[(size_t)16777216 + 16384 + (size_t)b * 256 + tid] = cx;  // final cx
  }
}

// ---------------------------------------------------------------------------
extern "C" void kernel_launch(void* const* d_in, const int* in_sizes, int n_in,
                              void* d_out, int out_size, void* d_ws, size_t ws_size,
                              hipStream_t stream) {
  const float* X = (const float*)d_in[0];      // [1024,64,256]
  const float* W = (const float*)d_in[1];      // [512,1024]
  const float* bias = (const float*)d_in[2];   // [1024]
  const float* beta = (const float*)d_in[3];   // [1]
  const float* noise = (const float*)d_in[4];  // [1024,64,256]
  float* out = (float*)d_out;

  char* ws = (char*)d_ws;
  _Float16* Gx = (_Float16*)ws;                        // 128 MB
  _Float16* WT = (_Float16*)(ws + (size_t)134217728);  // 1 MB

  // k_lstm uses 148.5KB dynamic LDS: raise the cap (not a stream op; safe
  // under graph capture).
  static const size_t kLstmSmem = 147456 + 4096 + 512;
  hipFuncSetAttribute((const void*)k_lstm,
                      hipFuncAttributeMaxDynamicSharedMemorySize,
                      (int)kLstmSmem);

  k_transpose_w<<<128, 256, 0, stream>>>(W, WT);
  k_gx_gemm<<<4096, 256, 0, stream>>>(X, WT, bias, Gx);
  k_lstm<<<64, 512, kLstmSmem, stream>>>(Gx, WT, noise, beta, out);
}

// Round 5
// 1781.636 us; speedup vs baseline: 1.0675x; 1.0675x over previous
//
#include <hip/hip_runtime.h>

// Problem constants: T=1024, B=64, D=256, H=256, 4H=1024, D+H=512.

typedef _Float16 half2_t __attribute__((ext_vector_type(2)));
typedef _Float16 half4_t __attribute__((ext_vector_type(4)));
typedef _Float16 half8_t __attribute__((ext_vector_type(8)));
typedef float floatx4 __attribute__((ext_vector_type(4)));

__device__ __forceinline__ float fdot2(unsigned h, unsigned w, float acc) {
#if __has_builtin(__builtin_amdgcn_fdot2)
  return __builtin_amdgcn_fdot2(__builtin_bit_cast(half2_t, h),
                                __builtin_bit_cast(half2_t, w), acc, false);
#else
  half2_t a = __builtin_bit_cast(half2_t, h);
  half2_t b = __builtin_bit_cast(half2_t, w);
  return acc + (float)a[0] * (float)b[0] + (float)a[1] * (float)b[1];
#endif
}

__device__ __forceinline__ floatx4 mfma16x16x32(half8_t a, half8_t b, floatx4 c) {
#if __has_builtin(__builtin_amdgcn_mfma_f32_16x16x32_f16)
  return __builtin_amdgcn_mfma_f32_16x16x32_f16(a, b, c, 0, 0, 0);
#else
  half4_t alo = __builtin_shufflevector(a, a, 0, 1, 2, 3);
  half4_t ahi = __builtin_shufflevector(a, a, 4, 5, 6, 7);
  half4_t blo = __builtin_shufflevector(b, b, 0, 1, 2, 3);
  half4_t bhi = __builtin_shufflevector(b, b, 4, 5, 6, 7);
  c = __builtin_amdgcn_mfma_f32_16x16x16f16(alo, blo, c, 0, 0, 0);
  c = __builtin_amdgcn_mfma_f32_16x16x16f16(ahi, bhi, c, 0, 0, 0);
  return c;
#endif
}

__device__ __forceinline__ float sigm(float x) { return 1.f / (1.f + __expf(-x)); }
__device__ __forceinline__ float tanh_(float x) {
  float ax = fabsf(x);
  float e = __expf(-2.f * ax);
  float t = (1.f - e) / (1.f + e);
  return x < 0.f ? -t : t;
}

// ---------------------------------------------------------------------------
// K0: W [512][1024] f32 (row-major) -> WT [1024][512] fp16 (col-major of W).
// ---------------------------------------------------------------------------
__global__ __launch_bounds__(256) void k_transpose_w(const float* __restrict__ W,
                                                     _Float16* __restrict__ WT) {
  __shared__ float tile[64][65];
  const int bx = blockIdx.x & 15;
  const int by = blockIdx.x >> 4;
  const int c0 = bx * 64, r0 = by * 64;
  const int tid = threadIdx.x;
#pragma unroll
  for (int i = 0; i < 16; ++i) {
    int idx = tid + i * 256;
    int r = idx >> 6, c = idx & 63;
    tile[r][c] = W[(size_t)(r0 + r) * 1024 + c0 + c];
  }
  __syncthreads();
#pragma unroll
  for (int i = 0; i < 16; ++i) {
    int idx = tid + i * 256;
    int c = idx >> 6, r = idx & 63;
    WT[(size_t)(c0 + c) * 512 + r0 + r] = (_Float16)tile[r][c];
  }
}

// ---------------------------------------------------------------------------
// K1: Gx = X @ W[:256,:] + b, fp16 MFMA, f32 accum, fp16 out. BM=BN=128 BK=32.
// ---------------------------------------------------------------------------
__global__ __launch_bounds__(256) void k_gx_gemm(const float* __restrict__ X,
                                                 const _Float16* __restrict__ WT,
                                                 const float* __restrict__ bias,
                                                 _Float16* __restrict__ Gx) {
  const int nb = blockIdx.x & 7;
  const int mb = blockIdx.x >> 3;
  const int m0 = mb * 128, n0 = nb * 128;
  __shared__ __align__(16) _Float16 As[128 * 40];
  __shared__ __align__(16) _Float16 Bs[128 * 40];
  const int tid = threadIdx.x;
  const int wave = tid >> 6, lane = tid & 63;
  const int wm = (wave >> 1) * 64, wn = (wave & 1) * 64;
  const int lm = lane & 15, lg = lane >> 4;
  const int srow = tid >> 1, skh = (tid & 1) * 16;
  floatx4 acc[4][4] = {};
  for (int kt = 0; kt < 256; kt += 32) {
    __syncthreads();
    {
      const float* src = X + (size_t)(m0 + srow) * 256 + kt + skh;
      float4 f0 = ((const float4*)src)[0];
      float4 f1 = ((const float4*)src)[1];
      float4 f2 = ((const float4*)src)[2];
      float4 f3 = ((const float4*)src)[3];
      half8_t h0 = {(_Float16)f0.x, (_Float16)f0.y, (_Float16)f0.z, (_Float16)f0.w,
                    (_Float16)f1.x, (_Float16)f1.y, (_Float16)f1.z, (_Float16)f1.w};
      half8_t h1 = {(_Float16)f2.x, (_Float16)f2.y, (_Float16)f2.z, (_Float16)f2.w,
                    (_Float16)f3.x, (_Float16)f3.y, (_Float16)f3.z, (_Float16)f3.w};
      *(half8_t*)&As[srow * 40 + skh] = h0;
      *(half8_t*)&As[srow * 40 + skh + 8] = h1;
      const _Float16* bsrc = WT + (size_t)(n0 + srow) * 512 + kt + skh;
      half8_t b0 = ((const half8_t*)bsrc)[0];
      half8_t b1 = ((const half8_t*)bsrc)[1];
      *(half8_t*)&Bs[srow * 40 + skh] = b0;
      *(half8_t*)&Bs[srow * 40 + skh + 8] = b1;
    }
    __syncthreads();
    half8_t af[4], bf[4];
#pragma unroll
    for (int mf = 0; mf < 4; ++mf)
      af[mf] = *(const half8_t*)&As[(wm + mf * 16 + lm) * 40 + lg * 8];
#pragma unroll
    for (int nf = 0; nf < 4; ++nf)
      bf[nf] = *(const half8_t*)&Bs[(wn + nf * 16 + lm) * 40 + lg * 8];
#pragma unroll
    for (int mf = 0; mf < 4; ++mf)
#pragma unroll
      for (int nf = 0; nf < 4; ++nf)
        acc[mf][nf] = mfma16x16x32(af[mf], bf[nf], acc[mf][nf]);
  }
#pragma unroll
  for (int mf = 0; mf < 4; ++mf) {
#pragma unroll
    for (int nf = 0; nf < 4; ++nf) {
      const int gm = m0 + wm + mf * 16 + lg * 4;
      const int gn = n0 + wn + nf * 16 + lm;
      const float bv = bias[gn];
#pragma unroll
      for (int i = 0; i < 4; ++i)
        Gx[(size_t)(gm + i) * 1024 + gn] = (_Float16)(acc[mf][nf][i] + bv);
    }
  }
}

// ---------------------------------------------------------------------------
// K2: persistent per-batch LSTM recurrence. 64 blocks (1/CU), 512 threads.
// Thread owns gate columns {tid, tid+512}.
//
// KEY CHANGE vs R2-R4: LDS is STATIC (152,064 B). With dynamic LDS the
// compiler saw LDS=0 (rocprof LDS_Block_Size=0), assumed multi-block/CU
// occupancy, pinned the allocator at 128 VGPRs, and spilled the 184-dword
// weight array to scratch -> 368KB/block/step reload through the CU VMEM
// port = the 1.78us/step. Static 148.5KB forces "1 block/CU" into the
// occupancy model -> 8 waves/CU = 2/SIMD -> 256-VGPR budget (m214
// precedent: 249 VGPRs at 512 thr with large static LDS).
//
//   rows 0..183   -> 23 uint4 x 2 cols = 184 VGPRs per thread
//   rows 184..255 -> static LDS, 1024 cols x 9 uint4 = 144KB.
//                    Column stride 144B -> odd dword stride -> 2 lanes/bank
//                    = conflict-free (verified: SQ_LDS_BANK_CONFLICT=0).
// hx in LDS as fp16x2, uniform-address broadcast reads.
// Gx/noise prefetched one step ahead.
// ---------------------------------------------------------------------------
__global__ __attribute__((amdgpu_flat_work_group_size(512, 512),
                          amdgpu_waves_per_eu(2, 2))) void
k_lstm(const _Float16* __restrict__ Gx, const _Float16* __restrict__ WT,
       const float* __restrict__ noise, const float* __restrict__ beta_p,
       float* __restrict__ out) {
  __shared__ __align__(16) uint4 wl[1024 * 9];  // 144KB weight rows 184..255
  __shared__ float gates[1024];                 // 4KB
  __shared__ unsigned hx2[128];                 // 512B: 256 fp16 h values

  const int b = blockIdx.x;
  const int tid = threadIdx.x;
  const float beta = beta_p[0];
  const int c0 = tid, c1 = tid + 512;

  // Stage weights. WT row offset +256 = h-part of the fused matrix.
  const uint4* p0 = (const uint4*)(WT + (size_t)c0 * 512 + 256);
  const uint4* p1 = (const uint4*)(WT + (size_t)c1 * 512 + 256);
  uint4 w0[23], w1[23];
#pragma unroll
  for (int i = 0; i < 23; ++i) w0[i] = p0[i];
#pragma unroll
  for (int i = 0; i < 23; ++i) w1[i] = p1[i];
  uint4* wlp0 = wl + c0 * 9;
  uint4* wlp1 = wl + c1 * 9;
#pragma unroll
  for (int i = 0; i < 9; ++i) wlp0[i] = p0[23 + i];
#pragma unroll
  for (int i = 0; i < 9; ++i) wlp1[i] = p1[23 + i];
  if (tid < 128) hx2[tid] = 0u;
  float cx = 0.f, hlast = 0.f;
  __syncthreads();

  const _Float16* gp0 = Gx + (size_t)b * 1024 + c0;
  const _Float16* gp1 = Gx + (size_t)b * 1024 + c1;
  const float* nzp = noise + (size_t)b * 256 + (tid & 255);
  float* outp = out + (size_t)b * 256 + tid;  // only used when tid<256

  // Prefetch step 0.
  float g0 = (float)gp0[0];
  float g1 = (float)gp1[0];
  float nz = nzp[0];

  for (int t = 0; t < 1024; ++t) {
    // Prefetch step t+1 (hides under the fdot2 phase).
    float g0n = 0.f, g1n = 0.f, nzn = 0.f;
    if (t < 1023) {
      g0n = (float)gp0[65536];
      g1n = (float)gp1[65536];
      nzn = nzp[16384];
    }

    float a0e = 0.f, a0o = 0.f, a1e = 0.f, a1o = 0.f;
    // Register-resident rows 0..183: chunk i = rows 8i..8i+7.
#pragma unroll
    for (int i = 0; i < 23; ++i) {
      uint4 h4 = *(const uint4*)&hx2[i * 4];  // wave-uniform -> LDS broadcast
      a0e = fdot2(h4.x, w0[i].x, a0e);
      a0o = fdot2(h4.y, w0[i].y, a0o);
      a0e = fdot2(h4.z, w0[i].z, a0e);
      a0o = fdot2(h4.w, w0[i].w, a0o);
      a1e = fdot2(h4.x, w1[i].x, a1e);
      a1o = fdot2(h4.y, w1[i].y, a1o);
      a1e = fdot2(h4.z, w1[i].z, a1e);
      a1o = fdot2(h4.w, w1[i].w, a1o);
    }
    // LDS-resident rows 184..255: chunks 23..31.
#pragma unroll
    for (int i = 0; i < 9; ++i) {
      uint4 h4 = *(const uint4*)&hx2[92 + i * 4];
      uint4 wa = wlp0[i];
      uint4 wb = wlp1[i];
      a0e = fdot2(h4.x, wa.x, a0e);
      a0o = fdot2(h4.y, wa.y, a0o);
      a0e = fdot2(h4.z, wa.z, a0e);
      a0o = fdot2(h4.w, wa.w, a0o);
      a1e = fdot2(h4.x, wb.x, a1e);
      a1o = fdot2(h4.y, wb.y, a1o);
      a1e = fdot2(h4.z, wb.z, a1e);
      a1o = fdot2(h4.w, wb.w, a1o);
    }
    gates[c0] = a0e + a0o + g0;
    gates[c1] = a1e + a1o + g1;
    __syncthreads();  // gates ready; all hx2 reads for step t done

    if (tid < 256) {
      float f = sigm(gates[tid]);
      float ii = sigm(gates[tid + 256]);
      float gg = tanh_(gates[tid + 512]);
      float oo = sigm(gates[tid + 768]);
      cx = f * cx + ii * gg;
      float h = oo * tanh_(cx) + beta * nz;
      hlast = h;
      outp[0] = h;
      ((_Float16*)hx2)[tid] = (_Float16)h;  // publish hx for step t+1
    }
    g0 = g0n; g1 = g1n; nz = nzn;
    gp0 += 65536; gp1 += 65536; nzp += 16384; outp += 16384;
    __syncthreads();  // hx2 ready
  }

  if (tid < 256) {
    out[(size_t)16777216 + (size_t)b * 256 + tid] = hlast;       // final hx
    out[(size_t)16777216 + 16384 + (size_t)b * 256 + tid] = cx;  // final cx
  }
}

// ---------------------------------------------------------------------------
extern "C" void kernel_launch(void* const* d_in, const int* in_sizes, int n_in,
                              void* d_out, int out_size, void* d_ws, size_t ws_size,
                              hipStream_t stream) {
  const float* X = (const float*)d_in[0];      // [1024,64,256]
  const float* W = (const float*)d_in[1];      // [512,1024]
  const float* bias = (const float*)d_in[2];   // [1024]
  const float* beta = (const float*)d_in[3];   // [1]
  const float* noise = (const float*)d_in[4];  // [1024,64,256]
  float* out = (float*)d_out;

  char* ws = (char*)d_ws;
  _Float16* Gx = (_Float16*)ws;                        // 128 MB
  _Float16* WT = (_Float16*)(ws + (size_t)134217728);  // 1 MB

  k_transpose_w<<<128, 256, 0, stream>>>(W, WT);
  k_gx_gemm<<<4096, 256, 0, stream>>>(X, WT, bias, Gx);
  k_lstm<<<64, 512, 0, stream>>>(Gx, WT, noise, beta, out);
}